// Round 3
// baseline (15414.169 us; speedup 1.0000x reference)
//
#include <hip/hip_runtime.h>
#include <hip/hip_bf16.h>
#include <math.h>

// Problem constants (from reference)
#define LAYERS 2
#define BATCH  128
#define TT     64
#define HID    1024
#define VOC    10000
#define ISZ    2048
#define XW     1024   // x-part width = EMB+CNN = 1024 (== HID)

typedef __attribute__((ext_vector_type(8))) short  short8v;  // 8x bf16 MFMA frag
typedef __attribute__((ext_vector_type(4))) float  float4v;  // 4x f32 MFMA acc

// ---------------- workspace layout (float offsets) ----------------
constexpr size_t BH      = (size_t)BATCH * HID;            // 131072
constexpr size_t LW      = (size_t)ISZ * HID;              // 2097152 per-layer weight elems
constexpr size_t OFF_X0  = 0;
constexpr size_t OFF_WCP = OFF_X0  + BH;                   // Wc + bc, [L][ISZ][HID] f32
constexpr size_t OFF_PXU = OFF_WCP + (size_t)LAYERS * LW;
constexpr size_t OFF_PXR = OFF_PXU + BH;
constexpr size_t OFF_PXC = OFF_PXR + BH;
constexpr size_t OFF_H0  = OFF_PXC + BH;                   // 2 ping-pong buffers
constexpr size_t OFF_H1  = OFF_H0  + 2 * BH;
constexpr size_t OFF_U   = OFF_H1  + 2 * BH;
constexpr size_t OFF_R   = OFF_U   + BH;
constexpr size_t OFF_HALL= OFF_R   + BH;                   // bf16 [T][B][HID] -> T*BH/2 floats
constexpr size_t OFF_WOB = OFF_HALL + (size_t)TT * BH / 2; // bf16 [V][HID]   -> V*HID/2 floats
// total = OFF_WOB + VOC*HID/2  ~= 14.8M floats ~= 59 MB

// ---------------- small prep kernels ----------------
__global__ void k_x0(const int* __restrict__ tok, const float* __restrict__ emb,
                     const float* __restrict__ cnn, float* __restrict__ x0) {
  int i = blockIdx.x * 256 + threadIdx.x;          // B*HID = 131072
  if (i >= BATCH * HID) return;
  int b = i >> 10, j = i & 1023;
  float v;
  if (j < 512) v = emb[(size_t)tok[b * TT] * 512 + j];   // tokens[:,0] only (ref quirk)
  else         v = cnn[b * 512 + (j - 512)];
  x0[i] = v;
}

__global__ void k_hinit(const float* __restrict__ hi, float* __restrict__ h0,
                        float* __restrict__ h1) {
  int i = blockIdx.x * 256 + threadIdx.x;          // 131072
  if (i >= BATCH * HID) return;
  h0[i] = hi[i];
  h1[i] = hi[BATCH * HID + i];
}

// Wc' = Wc + bc  (bias broadcast over rows == the reference's quirk, exactly)
__global__ void k_wcp(const float* __restrict__ Wc, const float* __restrict__ bc,
                      float* __restrict__ Wcp) {
  int i4 = blockIdx.x * 256 + threadIdx.x;         // (2*2048*1024)/4 = 1048576
  if (i4 >= (int)(LAYERS * LW / 4)) return;
  size_t e = (size_t)i4 * 4;
  int l = (int)(e >> 21);                          // ISZ*HID = 2^21
  int j = (int)(e & 1023);
  float4 w = *(const float4*)(Wc + e);
  const float* bp = bc + l * HID + j;
  w.x += bp[0]; w.y += bp[1]; w.z += bp[2]; w.w += bp[3];
  *(float4*)(Wcp + e) = w;
}

__global__ void k_woutb(const float* __restrict__ W, __hip_bfloat16* __restrict__ o) {
  int i4 = blockIdx.x * 256 + threadIdx.x;         // 10240000/4 = 2560000
  if (i4 >= VOC * HID / 4) return;
  size_t e = (size_t)i4 * 4;
  float4 w = *(const float4*)(W + e);
  o[e + 0] = __float2bfloat16(w.x);
  o[e + 1] = __float2bfloat16(w.y);
  o[e + 2] = __float2bfloat16(w.z);
  o[e + 3] = __float2bfloat16(w.w);
}

__global__ void k_final(const float* __restrict__ h0f, const float* __restrict__ h1f,
                        float* __restrict__ out) {
  int i = blockIdx.x * 256 + threadIdx.x;          // 131072
  if (i >= BATCH * HID) return;
  out[i] = h0f[i];
  out[BATCH * HID + i] = h1f[i];
}

// ---------------- fp32 phase GEMM core ----------------
// M=128, N per gate=1024, K=1024 per A-slab. 256 threads.
// 64-row path (u/r/px): tile 64x16, 2x2 outputs/thread.
// 32-row path (c):      tile 32x16, 1x2 outputs/thread, grid 256 (full fill).
#define BM 64
#define BN 16
#define BK 32

__device__ __forceinline__ void stage_A(const float* __restrict__ A, const float* __restrict__ Am,
                                        int m0, int k0, float (&Al)[BM][36], int tid) {
  int ar = tid >> 2;               // 0..63
  int ac = (tid & 3) * 8;          // 0,8,16,24
  const float* p = A + (size_t)(m0 + ar) * HID + k0 + ac;
  float4 v0 = *(const float4*)p;
  float4 v1 = *(const float4*)(p + 4);
  if (Am) {                        // elementwise r*h on the fly
    const float* q = Am + (size_t)(m0 + ar) * HID + k0 + ac;
    float4 u0 = *(const float4*)q;
    float4 u1 = *(const float4*)(q + 4);
    v0.x *= u0.x; v0.y *= u0.y; v0.z *= u0.z; v0.w *= u0.w;
    v1.x *= u1.x; v1.y *= u1.y; v1.z *= u1.z; v1.w *= u1.w;
  }
  *(float4*)&Al[ar][ac]     = v0;
  *(float4*)&Al[ar][ac + 4] = v1;
}

__device__ __forceinline__ void stage_A32(const float* __restrict__ A, const float* __restrict__ Am,
                                          int m0, int k0, float (&Al)[32][36], int tid) {
  int ar = tid >> 3;               // 0..31
  int ac = (tid & 7) * 4;          // 0..28
  const float* p = A + (size_t)(m0 + ar) * HID + k0 + ac;
  float4 v0 = *(const float4*)p;
  if (Am) {
    const float* q = Am + (size_t)(m0 + ar) * HID + k0 + ac;
    float4 u0 = *(const float4*)q;
    v0.x *= u0.x; v0.y *= u0.y; v0.z *= u0.z; v0.w *= u0.w;
  }
  *(float4*)&Al[ar][ac] = v0;
}

__device__ __forceinline__ void stage_W(const float* __restrict__ W, int k0, int n0,
                                        float (&Wl)[BN][36], int tid) {
  if (tid < 128) {
    int wk = tid >> 2, wq = tid & 3;   // wk 0..31, wq 0..3
    const float* p = W + (size_t)(k0 + wk) * HID + n0 + wq * 4;
    float4 v = *(const float4*)p;
    Wl[wq * 4 + 0][wk] = v.x;
    Wl[wq * 4 + 1][wk] = v.y;
    Wl[wq * 4 + 2][wk] = v.z;
    Wl[wq * 4 + 3][wk] = v.w;
  }
}

__device__ __forceinline__ void mm_chunk(const float (&Al)[BM][36], const float (&Wl)[BN][36],
                                         int rp, int cp, float (&acc)[2][2]) {
#pragma unroll
  for (int k4 = 0; k4 < BK / 4; ++k4) {
    float4 a0 = *(const float4*)&Al[2 * rp][k4 * 4];
    float4 a1 = *(const float4*)&Al[2 * rp + 1][k4 * 4];
    float4 w0 = *(const float4*)&Wl[2 * cp][k4 * 4];
    float4 w1 = *(const float4*)&Wl[2 * cp + 1][k4 * 4];
    acc[0][0] += a0.x * w0.x + a0.y * w0.y + a0.z * w0.z + a0.w * w0.w;
    acc[0][1] += a0.x * w1.x + a0.y * w1.y + a0.z * w1.z + a0.w * w1.w;
    acc[1][0] += a1.x * w0.x + a1.y * w0.y + a1.z * w0.z + a1.w * w0.w;
    acc[1][1] += a1.x * w1.x + a1.y * w1.y + a1.z * w1.z + a1.w * w1.w;
  }
}

__device__ __forceinline__ void mm_chunk32(const float (&Al)[32][36], const float (&Wl)[BN][36],
                                           int rp, int cp, float (&acc)[2]) {
#pragma unroll
  for (int k4 = 0; k4 < BK / 4; ++k4) {
    float4 a0 = *(const float4*)&Al[rp][k4 * 4];
    float4 w0 = *(const float4*)&Wl[2 * cp][k4 * 4];
    float4 w1 = *(const float4*)&Wl[2 * cp + 1][k4 * 4];
    acc[0] += a0.x * w0.x + a0.y * w0.y + a0.z * w0.z + a0.w * w0.w;
    acc[1] += a0.x * w1.x + a0.y * w1.y + a0.z * w1.z + a0.w * w1.w;
  }
}

__device__ __forceinline__ void gemm_acc(
    const float* A1, const float* Am1, const float* W1,
    const float* A2, const float* Am2, const float* W2,
    int m0, int n0, int tid, int rp, int cp,
    float (&Al)[BM][36], float (&Wl)[BN][36], float (&acc)[2][2]) {
  for (int p = 0; p < 2; ++p) {
    const float* A  = p ? A2  : A1;
    if (!A) break;
    const float* Am = p ? Am2 : Am1;
    const float* W  = p ? W2  : W1;
    for (int k0 = 0; k0 < 1024; k0 += BK) {
      stage_A(A, Am, m0, k0, Al, tid);
      stage_W(W, k0, n0, Wl, tid);
      __syncthreads();
      mm_chunk(Al, Wl, rp, cp, acc);
      __syncthreads();
    }
  }
}

__device__ __forceinline__ void gemm_acc32(
    const float* A1, const float* Am1, const float* W1,
    const float* A2, const float* Am2, const float* W2,
    int m0, int n0, int tid, int rp, int cp,
    float (&Al)[32][36], float (&Wl)[BN][36], float (&acc)[2]) {
  for (int p = 0; p < 2; ++p) {
    const float* A  = p ? A2  : A1;
    if (!A) break;
    const float* Am = p ? Am2 : Am1;
    const float* W  = p ? W2  : W1;
    for (int k0 = 0; k0 < 1024; k0 += BK) {
      stage_A32(A, Am, m0, k0, Al, tid);
      stage_W(W, k0, n0, Wl, tid);
      __syncthreads();
      mm_chunk32(Al, Wl, rp, cp, acc);
      __syncthreads();
    }
  }
}

// u,r gates: out = sigmoid(pre? + A1@W1 (+ A2@W2) + bias?)  — grid 256 (2 gates x 2 mt x 64 nt)
__global__ __launch_bounds__(256) void k_ur(
    const float* __restrict__ A1, const float* __restrict__ A2,
    const float* W1u, const float* W2u, const float* W1r, const float* W2r,
    const float* preU, const float* preR, const float* biasU, const float* biasR,
    float* __restrict__ outU, float* __restrict__ outR) {
  __shared__ alignas(16) float Al[BM][36];
  __shared__ alignas(16) float Wl[BN][36];
  int bid = blockIdx.x;
  int gate = bid >> 7;
  int mt = (bid >> 6) & 1;
  int nt = bid & 63;
  int m0 = mt * BM, n0 = nt * BN;
  const float* W1   = gate ? W1r   : W1u;
  const float* W2   = gate ? W2r   : W2u;
  const float* pre  = gate ? preR  : preU;
  const float* bias = gate ? biasR : biasU;
  float* out        = gate ? outR  : outU;
  int tid = threadIdx.x;
  int cp = tid & 7, rp = tid >> 3;
  float acc[2][2] = {{0.f, 0.f}, {0.f, 0.f}};
  gemm_acc(A1, nullptr, W1, A2, nullptr, W2, m0, n0, tid, rp, cp, Al, Wl, acc);
#pragma unroll
  for (int i = 0; i < 2; ++i)
#pragma unroll
    for (int jj = 0; jj < 2; ++jj) {
      int row = m0 + 2 * rp + i, col = n0 + 2 * cp + jj;
      size_t idx = (size_t)row * HID + col;
      float v = acc[i][jj];
      if (pre)  v += pre[idx];
      if (bias) v += bias[col];
      out[idx] = 1.f / (1.f + expf(-v));
    }
}

// c gate + state update: c = tanh(pre? + [Ax@Wx] + (Rm*Hst)@Wh); hn = u*h + (1-u)*c
// grid 256 (4 mt x 64 nt), BM=32 so the whole GPU is filled.
__global__ __launch_bounds__(256) void k_cu(
    const float* __restrict__ Ax, const float* Wx,
    const float* __restrict__ Hst, const float* __restrict__ Rm, const float* Wh,
    const float* __restrict__ pre, const float* __restrict__ Ub,
    float* __restrict__ Hnew, __hip_bfloat16* __restrict__ hallT) {
  __shared__ alignas(16) float Al[32][36];
  __shared__ alignas(16) float Wl[BN][36];
  int bid = blockIdx.x;
  int mt = bid >> 6, nt = bid & 63;
  int m0 = mt * 32, n0 = nt * BN;
  int tid = threadIdx.x;
  int cp = tid & 7, rp = tid >> 3;
  float acc[2] = {0.f, 0.f};
  const float* A1 = Ax ? Ax      : Hst;
  const float* M1 = Ax ? nullptr : Rm;
  const float* W1 = Ax ? Wx      : Wh;
  const float* A2 = Ax ? Hst     : nullptr;
  const float* M2 = Ax ? Rm      : nullptr;
  const float* W2 = Ax ? Wh      : nullptr;
  gemm_acc32(A1, M1, W1, A2, M2, W2, m0, n0, tid, rp, cp, Al, Wl, acc);
  int row = m0 + rp;
#pragma unroll
  for (int jj = 0; jj < 2; ++jj) {
    int col = n0 + 2 * cp + jj;
    size_t idx = (size_t)row * HID + col;
    float c = acc[jj];
    if (pre) c += pre[idx];
    c = tanhf(c);
    float u = Ub[idx], h = Hst[idx];
    float hn = u * h + (1.f - u) * c;
    Hnew[idx] = hn;
    if (hallT) hallT[idx] = __float2bfloat16(hn);
  }
}

// one-time: px_{u,r,c} = x0 @ W_x-rows (+ bias for u,r) — grid 384 (3 gates x 2 mt x 64 nt)
__global__ __launch_bounds__(256) void k_px(
    const float* __restrict__ x0, const float* Wu0, const float* Wr0, const float* Wcp0,
    const float* bu0, const float* br0,
    float* __restrict__ pxu, float* __restrict__ pxr, float* __restrict__ pxc) {
  __shared__ alignas(16) float Al[BM][36];
  __shared__ alignas(16) float Wl[BN][36];
  int bid = blockIdx.x;
  int gate = bid >> 7;            // 0,1,2
  int rem = bid & 127;
  int mt = rem >> 6, nt = rem & 63;
  int m0 = mt * BM, n0 = nt * BN;
  const float* W    = (gate == 0) ? Wu0 : (gate == 1) ? Wr0 : Wcp0;
  const float* bias = (gate == 0) ? bu0 : (gate == 1) ? br0 : nullptr;
  float* out        = (gate == 0) ? pxu : (gate == 1) ? pxr : pxc;
  int tid = threadIdx.x;
  int cp = tid & 7, rp = tid >> 3;
  float acc[2][2] = {{0.f, 0.f}, {0.f, 0.f}};
  gemm_acc(x0, nullptr, W, nullptr, nullptr, nullptr, m0, n0, tid, rp, cp, Al, Wl, acc);
#pragma unroll
  for (int i = 0; i < 2; ++i)
#pragma unroll
    for (int jj = 0; jj < 2; ++jj) {
      int row = m0 + 2 * rp + i, col = n0 + 2 * cp + jj;
      size_t idx = (size_t)row * HID + col;
      float v = acc[i][jj];
      if (bias) v += bias[col];
      out[idx] = v;
    }
}

// ---------------- bf16 MFMA logits GEMM ----------------
// C[8192 x 10000] = hall_bf16[8192 x 1024] @ W_out_bf16[10000 x 1024]^T (NT, both K-contig)
// tile 128 x 80, 4 waves along M (wave tile 32x80 = 2x5 frags), no LDS (L2-fed).
__global__ __launch_bounds__(256) void k_logits(
    const short* __restrict__ Ab, const short* __restrict__ Bb,
    const float* __restrict__ bout, float* __restrict__ out) {
  int bid = blockIdx.x;                 // 64 * 125 = 8000
  int mt = bid / 125, nt = bid % 125;
  int wv = threadIdx.x >> 6, lane = threadIdx.x & 63;
  int lrow = lane & 15, kq = lane >> 4; // A/B frag: 8 contiguous k at kq*8
  int rowb = mt * 128 + wv * 32;
  int colb = nt * 80;
  float4v acc[2][5];
#pragma unroll
  for (int mi = 0; mi < 2; ++mi)
#pragma unroll
    for (int ni = 0; ni < 5; ++ni)
      acc[mi][ni] = (float4v){0.f, 0.f, 0.f, 0.f};

  const short* ap0 = Ab + (size_t)(rowb + lrow) * HID;
  const short* ap1 = ap0 + 16 * HID;
  const short* bp  = Bb + (size_t)(colb + lrow) * HID;
  for (int k0 = 0; k0 < HID; k0 += 32) {
    int k = k0 + kq * 8;
    short8v a0 = *(const short8v*)(ap0 + k);
    short8v a1 = *(const short8v*)(ap1 + k);
    short8v bf[5];
#pragma unroll
    for (int ni = 0; ni < 5; ++ni)
      bf[ni] = *(const short8v*)(bp + (size_t)ni * 16 * HID + k);
#pragma unroll
    for (int ni = 0; ni < 5; ++ni) {
      acc[0][ni] = __builtin_amdgcn_mfma_f32_16x16x32_bf16(a0, bf[ni], acc[0][ni], 0, 0, 0);
      acc[1][ni] = __builtin_amdgcn_mfma_f32_16x16x32_bf16(a1, bf[ni], acc[1][ni], 0, 0, 0);
    }
  }
  // C/D layout: col = lane&15, row = (lane>>4)*4 + reg  [guide m89/m91]
#pragma unroll
  for (int mi = 0; mi < 2; ++mi) {
    int rbase = rowb + mi * 16 + kq * 4;
#pragma unroll
    for (int ni = 0; ni < 5; ++ni) {
      int v = colb + ni * 16 + lrow;
      float bo = bout[v];
#pragma unroll
      for (int i = 0; i < 4; ++i) {
        int row = rbase + i;               // global M index = t*128 + b
        int t = row >> 7, b = row & 127;
        out[(size_t)b * TT * VOC + (size_t)t * VOC + v] = acc[mi][ni][i] + bo;
      }
    }
  }
}

// ---------------- launcher ----------------
extern "C" void kernel_launch(void* const* d_in, const int* in_sizes, int n_in,
                              void* d_out, int out_size, void* d_ws, size_t ws_size,
                              hipStream_t stream) {
  (void)in_sizes; (void)n_in; (void)out_size; (void)ws_size;
  const int*   tokens = (const int*)  d_in[0];
  const float* cnn    = (const float*)d_in[1];
  const float* hinit  = (const float*)d_in[2];
  const float* Wu     = (const float*)d_in[3];
  const float* bu     = (const float*)d_in[4];
  const float* Wr     = (const float*)d_in[5];
  const float* br     = (const float*)d_in[6];
  const float* Wc     = (const float*)d_in[7];
  const float* bc     = (const float*)d_in[8];
  const float* Wout   = (const float*)d_in[9];
  const float* bout   = (const float*)d_in[10];
  const float* emb    = (const float*)d_in[11];

  float* ws  = (float*)d_ws;
  float* x0  = ws + OFF_X0;
  float* Wcp = ws + OFF_WCP;
  float* pxu = ws + OFF_PXU;
  float* pxr = ws + OFF_PXR;
  float* pxc = ws + OFF_PXC;
  float* h0b = ws + OFF_H0;
  float* h1b = ws + OFF_H1;
  float* ub  = ws + OFF_U;
  float* rb  = ws + OFF_R;
  __hip_bfloat16* hall = (__hip_bfloat16*)(ws + OFF_HALL);
  __hip_bfloat16* wob  = (__hip_bfloat16*)(ws + OFF_WOB);

  float* outLogits = (float*)d_out;
  float* outH      = outLogits + (size_t)BATCH * TT * VOC;

  k_x0   <<<512,   256, 0, stream>>>(tokens, emb, cnn, x0);
  k_hinit<<<512,   256, 0, stream>>>(hinit, h0b, h1b);
  k_wcp  <<<4096,  256, 0, stream>>>(Wc, bc, Wcp);
  k_woutb<<<10000, 256, 0, stream>>>(Wout, wob);
  k_px   <<<384,   256, 0, stream>>>(x0, Wu, Wr, Wcp, bu, br, pxu, pxr, pxc);

  for (int t = 0; t < TT; ++t) {
    int in = t & 1, on = in ^ 1;
    float* h0i = h0b + (size_t)in * BH;
    float* h0o = h0b + (size_t)on * BH;
    float* h1i = h1b + (size_t)in * BH;
    float* h1o = h1b + (size_t)on * BH;
    // layer 0 (x-contribution precomputed in px_*)
    k_ur<<<256, 256, 0, stream>>>(h0i, nullptr,
        Wu + (size_t)XW * HID, nullptr, Wr + (size_t)XW * HID, nullptr,
        pxu, pxr, nullptr, nullptr, ub, rb);
    k_cu<<<256, 256, 0, stream>>>(nullptr, nullptr, h0i, rb, Wcp + (size_t)XW * HID,
        pxc, ub, h0o, nullptr);
    // layer 1 (x = fresh h0o)
    k_ur<<<256, 256, 0, stream>>>(h0o, h1i,
        Wu + LW, Wu + LW + (size_t)XW * HID,
        Wr + LW, Wr + LW + (size_t)XW * HID,
        nullptr, nullptr, bu + HID, br + HID, ub, rb);
    k_cu<<<256, 256, 0, stream>>>(h0o, Wcp + LW, h1i, rb, Wcp + LW + (size_t)XW * HID,
        nullptr, ub, h1o, hall + (size_t)t * BH);
  }

  k_logits<<<8000, 256, 0, stream>>>((const short*)hall, (const short*)wob, bout, outLogits);
  // t=63 wrote buffer 0 => final states live at buffer index 0
  k_final<<<512, 256, 0, stream>>>(h0b, h1b, outH);
}